// Round 14
// baseline (243.608 us; speedup 1.0000x reference)
//
#include <hip/hip_runtime.h>
#include <hip/hip_bf16.h>
#include <hip/hip_fp16.h>
#include <math.h>

#define BB 2
#define NPIX 131072            // 2*256*256

// ws layout (float indices unless _BYTE).  No pre-zeroing needed anywhere:
// all regions are fully overwritten every run (non-atomic partials).
#define WS_GP 0                // [512][1024] f32 G partials (2 MB)
#define WS_SP 524288           // [512][128]  f32 ssq partials (256 KB) [blk][q/k][64]
#define WS_M  589824           // 8192 ushort: Mt folded, MFMA-B-frag-swizzled (16 KB)
#define WS_M2_BYTE ((size_t)589824*4 + 16384)   // m2 bf16: NPIX*64*2 = 16.78 MB

typedef __attribute__((ext_vector_type(8))) short short8;
typedef __attribute__((ext_vector_type(4))) float f32x4;

__device__ __forceinline__ unsigned short f2bf(float f) {
    unsigned u = __float_as_uint(f);
    u += 0x7FFFu + ((u >> 16) & 1u);            // RNE
    return (unsigned short)(u >> 16);
}
__device__ __forceinline__ float bf2f(unsigned short s) {
    return __uint_as_float((unsigned)s << 16);
}
__device__ __forceinline__ void lds_fence() {
    __asm__ __volatile__("s_waitcnt lgkmcnt(0)" ::: "memory");
}
// fast transcendentals (r8: erff/expf -> __expf+v_rcp, confirmed −5us on k_fp)
__device__ __forceinline__ float fast_sigmoid(float a) {
    return __builtin_amdgcn_rcpf(1.f + __expf(-a));
}
__device__ __forceinline__ float fast_gelu(float x) {
    float y = 1.5957691216057308f * fmaf(0.044715f * x, x * x, x);
    return x * fast_sigmoid(y);
}

// ---------------------------------------------------------------------------
// K1 (MFMA, fused). 3-launch pipeline (k_prep deleted):
//  (a) each block self-swizzles the 5 weight mats into LDS B-frag order;
//  (b) G/ssq written as NON-ATOMIC per-block partials (no pre-zero needed);
//  (c) vm0 stored f16 PIXEL-LOCALLY: ushort index P*128+c = bytes
//      [P*256, P*256+128) — first half of pixel P's OWN f32 out row.
//      r13 FAILED (NaN) because P*64+c aliased OTHER pixels' f32 region ->
//      cross-block race with k_fp's final stores. P*128+c is block-local:
//      each k_fp block reads vm0 of its own pixels strictly before its own
//      overwrite (global->LDS->barrier->MFMA->store chain). Traffic still
//      halved: one aligned 128B line per pixel.
// LDS = 40(wswz) + 25.5(scr) + 8(ssq) = 73.5 KB -> 2 blocks/CU.
// ---------------------------------------------------------------------------
__global__ __launch_bounds__(256, 2) void k_fused(
    const float* __restrict__ x, const float* __restrict__ mask,
    const float* __restrict__ Wq, const float* __restrict__ Wk,
    const float* __restrict__ Wv, const float* __restrict__ w1,
    const float* __restrict__ w2,
    const float* __restrict__ b1, const float* __restrict__ b2,
    float* __restrict__ ws, float* __restrict__ out,
    __hip_bfloat16* __restrict__ m2out)
{
    __shared__ unsigned short wswz[20480];          // 40 KB
    __shared__ unsigned short scr[4][3264];         // 6.375 KB/wave (25.5 KB)
    __shared__ float s_ssq[4][2][4][64];            // 8 KB [w][mat][ot][lane]
    const int tid = threadIdx.x, lane = tid & 63, w = tid >> 6;
    const int quad = lane >> 4, col = lane & 15;
    const int blk = blockIdx.x;

    // self-swizzle weights: i = f*64 + l (f = matot*2+kh), 8 contiguous cols
    for (int i = tid; i < 2560; i += 256) {
        const int f = i >> 6, l = i & 63;
        const int matot = f >> 1, kh = f & 1;
        const int mat = matot >> 2, ot = matot & 3;
        const float* Wm = (mat == 0) ? Wq : (mat == 1) ? Wk :
                          (mat == 2) ? Wv : (mat == 3) ? w1 : w2;
        const int o = ot*16 + (l & 15);
        const int cc = kh*32 + ((l >> 4) & 3)*8;
        const float* src = Wm + o*64 + cc;
        float4 a0 = *(const float4*)src;
        float4 a1 = *(const float4*)(src + 4);
        short8 s8;
#pragma unroll
        for (int j = 0; j < 4; ++j) {
            s8[j]   = (short)f2bf((&a0.x)[j]);
            s8[4+j] = (short)f2bf((&a1.x)[j]);
        }
        *(short8*)&wswz[(size_t)i*8] = s8;
    }
    __syncthreads();

    float b1v[4], b2v[4];
#pragma unroll
    for (int ot = 0; ot < 4; ++ot) {
        b1v[ot] = b1[ot*16 + col];
        b2v[ot] = b2[ot*16 + col];
    }

#define WFRAG(matot, kh) (*(const short8*)&wswz[(((matot)*2 + (kh))*64 + lane)*8])

    f32x4 gacc[4];                      // G_h tiles: row d=quad*4+r, col e=lane&15
#pragma unroll
    for (int h = 0; h < 4; ++h) gacc[h] = (f32x4){0.f, 0.f, 0.f, 0.f};
    float ssq[2][4];                    // [mat][ot], channel = ot*16+col
#pragma unroll
    for (int mm = 0; mm < 2; ++mm)
#pragma unroll
        for (int ot = 0; ot < 4; ++ot) ssq[mm][ot] = 0.f;
    const short8 z8 = {0,0,0,0,0,0,0,0};
    unsigned short* S  = scr[w];
    unsigned short* S2 = scr[w] + 2112; // byte 4224, 16B aligned; m1/m2 region

    for (int t = 0; t < 4; ++t) {
        const int pbase = blk*256 + t*64 + w*16;

        // A-frags from global (fp32 -> bf16): A[m=col(px)][k=quad*8+j (+32kh)]
        short8 xA[2], mA[2];
        {
            const float* xs = x    + ((size_t)(pbase + col))*64 + quad*8;
            const float* ms = mask + ((size_t)(pbase + col))*64 + quad*8;
#pragma unroll
            for (int kh = 0; kh < 2; ++kh) {
                float4 a0 = *(const float4*)(xs + kh*32);
                float4 a1 = *(const float4*)(xs + kh*32 + 4);
                float4 b0 = *(const float4*)(ms + kh*32);
                float4 b1f = *(const float4*)(ms + kh*32 + 4);
#pragma unroll
                for (int j = 0; j < 4; ++j) {
                    xA[kh][j]   = (short)f2bf((&a0.x)[j]);
                    xA[kh][4+j] = (short)f2bf((&a1.x)[j]);
                    mA[kh][j]   = (short)f2bf((&b0.x)[j]);
                    mA[kh][4+j] = (short)f2bf((&b1f.x)[j]);
                }
            }
        }

        // Phase A: q,k -> S_t[mat][c][24] bf16 (transposed), ssq in-register
#pragma unroll
        for (int mm = 0; mm < 2; ++mm) {
#pragma unroll
            for (int ot = 0; ot < 4; ++ot) {
                f32x4 a = {0.f, 0.f, 0.f, 0.f};
                a = __builtin_amdgcn_mfma_f32_16x16x32_bf16(xA[0], WFRAG(mm*4+ot,0), a, 0,0,0);
                a = __builtin_amdgcn_mfma_f32_16x16x32_bf16(xA[1], WFRAG(mm*4+ot,1), a, 0,0,0);
#pragma unroll
                for (int r = 0; r < 4; ++r) {
                    S[mm*1536 + (ot*16 + col)*24 + quad*4 + r] = f2bf(a[r]);
                    ssq[mm][ot] = fmaf(a[r], a[r], ssq[mm][ot]);
                }
            }
        }
        __builtin_amdgcn_wave_barrier();

        // Gram via MFMA: G_h[d][e] += sum_p K[p][h16+d]*Q[p][h16+e]
        {
            const int gb = (quad & 1) * 8;
#pragma unroll
            for (int h = 0; h < 4; ++h) {
                short8 aq = *(const short8*)&S[(h*16 + col)*24 + gb];
                short8 ak = *(const short8*)&S[1536 + (h*16 + col)*24 + gb];
                if (quad >= 2) { aq = z8; ak = z8; }
                gacc[h] = __builtin_amdgcn_mfma_f32_16x16x32_bf16(ak, aq, gacc[h], 0,0,0);
            }
        }
        lds_fence();                    // Gram reads done before S_t reused

        // v, m1
        f32x4 vfr[4], m1fr[4];
#pragma unroll
        for (int ot = 0; ot < 4; ++ot) {
            f32x4 a = {0.f, 0.f, 0.f, 0.f};
            a = __builtin_amdgcn_mfma_f32_16x16x32_bf16(xA[0], WFRAG(8+ot,0), a, 0,0,0);
            a = __builtin_amdgcn_mfma_f32_16x16x32_bf16(xA[1], WFRAG(8+ot,1), a, 0,0,0);
            vfr[ot] = a;
        }
#pragma unroll
        for (int ot = 0; ot < 4; ++ot) {
            f32x4 a = {0.f, 0.f, 0.f, 0.f};
            a = __builtin_amdgcn_mfma_f32_16x16x32_bf16(mA[0], WFRAG(12+ot,0), a, 0,0,0);
            a = __builtin_amdgcn_mfma_f32_16x16x32_bf16(mA[1], WFRAG(12+ot,1), a, 0,0,0);
#pragma unroll
            for (int r = 0; r < 4; ++r) a[r] += b1v[ot];
            m1fr[ot] = a;
        }

        // Phase B: vm0 fp32 [16][66] in S, then f16-packed PIXEL-LOCAL stores
        float* vscr = (float*)S;
#pragma unroll
        for (int ot = 0; ot < 4; ++ot)
#pragma unroll
            for (int r = 0; r < 4; ++r)
                vscr[(quad*4+r)*66 + ot*16 + col] = vfr[ot][r] * m1fr[ot][r];
        __builtin_amdgcn_wave_barrier();
        {
            unsigned short* o16 = (unsigned short*)out;
            const int rb = lane >> 5, ci = (lane & 31)*2;
#pragma unroll
            for (int pp = 0; pp < 8; ++pp) {
                const int row = pp*2 + rb;
                float2 v2 = *(const float2*)&vscr[row*66 + ci];
                unsigned pk = (unsigned)__half_as_ushort(__float2half(v2.x))
                            | ((unsigned)__half_as_ushort(__float2half(v2.y)) << 16);
                *(unsigned*)&o16[((size_t)(pbase + row))*128 + ci] = pk;
            }
        }
        // no fence: Phase C writes S2 (disjoint from vscr)

        // Phase C: m1 bf16 [16][72] in S2 -> A-frags for m2
#pragma unroll
        for (int ot = 0; ot < 4; ++ot)
#pragma unroll
            for (int r = 0; r < 4; ++r)
                S2[(quad*4+r)*72 + ot*16 + col] = f2bf(m1fr[ot][r]);
        __builtin_amdgcn_wave_barrier();
        short8 a2[2];
#pragma unroll
        for (int kh = 0; kh < 2; ++kh)
            a2[kh] = *(const short8*)&S2[col*72 + kh*32 + quad*8];
        lds_fence();                    // a2 reads done before S2 overwritten

        // Phase D: m2 mfma, bf16 [16][72] in S2, coalesced packed-uint stores
#pragma unroll
        for (int ot = 0; ot < 4; ++ot) {
            f32x4 a = {0.f, 0.f, 0.f, 0.f};
            a = __builtin_amdgcn_mfma_f32_16x16x32_bf16(a2[0], WFRAG(16+ot,0), a, 0,0,0);
            a = __builtin_amdgcn_mfma_f32_16x16x32_bf16(a2[1], WFRAG(16+ot,1), a, 0,0,0);
#pragma unroll
            for (int r = 0; r < 4; ++r)
                S2[(quad*4+r)*72 + ot*16 + col] = f2bf(a[r] + b2v[ot]);
        }
        __builtin_amdgcn_wave_barrier();
        {
            unsigned short* m2u = (unsigned short*)m2out;
            const int rb = lane >> 5, ci = (lane & 31)*2;
#pragma unroll
            for (int pp = 0; pp < 8; ++pp) {
                const int row = pp*2 + rb;
                unsigned vv = *(const unsigned*)&S2[row*72 + ci];
                *(unsigned*)&m2u[((size_t)(pbase + row))*64 + ci] = vv;
            }
        }
        lds_fence();                    // all reads done before next-iter A
    }

    __syncthreads();                    // all waves done with scr

    // two-phase block reduction of G; then NON-ATOMIC partial writes
    float* gr = (float*)&scr[0][0];     // 2048 floats (8KB) in 25.5KB scr
    if (w < 2) {
#pragma unroll
        for (int h = 0; h < 4; ++h)
#pragma unroll
            for (int r = 0; r < 4; ++r)
                gr[w*1024 + (h*16 + quad*4 + r)*16 + col] = gacc[h][r];
    }
#pragma unroll
    for (int mm = 0; mm < 2; ++mm)
#pragma unroll
        for (int ot = 0; ot < 4; ++ot)
            s_ssq[w][mm][ot][lane] = ssq[mm][ot];
    __syncthreads();
    if (w >= 2) {
#pragma unroll
        for (int h = 0; h < 4; ++h)
#pragma unroll
            for (int r = 0; r < 4; ++r)
                gr[(w-2)*1024 + (h*16 + quad*4 + r)*16 + col] += gacc[h][r];
    }
    __syncthreads();
    float* Gp = ws + WS_GP + (size_t)blk*1024;
    for (int idx = tid; idx < 1024; idx += 256)
        Gp[idx] = gr[idx] + gr[1024 + idx];
    if (tid < 128) {
        const int which = tid >> 6, cidx = tid & 63;
        const int ot = cidx >> 4, cl = cidx & 15;
        float s = 0.f;
#pragma unroll
        for (int wv = 0; wv < 4; ++wv)
#pragma unroll
            for (int q = 0; q < 4; ++q)
                s += s_ssq[wv][which][ot][q*16 + cl];
        ws[WS_SP + (size_t)blk*128 + which*64 + cidx] = s;
    }
#undef WFRAG
}

// ---------------------------------------------------------------------------
// K2: reduce 256 per-block G/ssq partials (coalesced), softmax over
// normalized Gram, folded with Wp; Mt written as bf16 MFMA-B-frags.
// ---------------------------------------------------------------------------
__global__ __launch_bounds__(256) void k_attn(const float* __restrict__ rescale,
    const float* __restrict__ Wp, float* __restrict__ ws)
{
    __shared__ float sG[1024];          // reduced Gram [c=h*16+d][e]
    __shared__ float sS[128];           // reduced ssq  [q/k][64]
    __shared__ float sAtt[1024];        // [h][d][e]
    const int b = blockIdx.x, t = threadIdx.x;
    const int d = t >> 4, e = t & 15;

    for (int idx = t; idx < 1024; idx += 256) {
        float s = 0.f;
        const float* p = ws + WS_GP + (size_t)(b*256)*1024 + idx;
        for (int j = 0; j < 256; ++j) s += p[(size_t)j*1024];
        sG[idx] = s;
    }
    if (t < 128) {
        float s = 0.f;
        const float* p = ws + WS_SP + (size_t)(b*256)*128 + t;
        for (int j = 0; j < 256; ++j) s += p[(size_t)j*128];
        sS[t] = s;
    }
    __syncthreads();

#pragma unroll
    for (int h = 0; h < 4; ++h) {
        float g   = sG[(h*16 + d)*16 + e];
        float nk2 = sS[64 + h*16 + d];
        float nq2 = sS[ 0 + h*16 + e];
        float nk = fmaxf(sqrtf(nk2), 1e-12f);
        float nq = fmaxf(sqrtf(nq2), 1e-12f);
        float val = g / (nk*nq) * rescale[h];
        float m = val;
        for (int off = 1; off < 16; off <<= 1) m = fmaxf(m, __shfl_xor(m, off, 16));
        float ev = expf(val - m);
        float s2 = ev;
        for (int off = 1; off < 16; off <<= 1) s2 += __shfl_xor(s2, off, 16);
        sAtt[h*256 + d*16 + e] = ev / s2;
    }
    __syncthreads();
    // Mt[c][o] = sum_d Wp[o][h*16+d]*att[h][d][e(c)], written B-frag-swizzled
    unsigned short* Mtw = (unsigned short*)(ws + WS_M) + (size_t)b*4096;
    for (int i = t; i < 4096; i += 256) {
        const int f = i >> 9, l = (i >> 3) & 63, j = i & 7;
        const int ot = f >> 1, kh = f & 1;
        const int o = ot*16 + (l & 15);
        const int cc = kh*32 + ((l >> 4) & 3)*8 + j;
        const int h = cc >> 4, ee = cc & 15;
        float acc = 0.f;
#pragma unroll
        for (int d2 = 0; d2 < 16; ++d2)
            acc = fmaf(Wp[o*64 + h*16 + d2], sAtt[h*256 + d2*16 + ee], acc);
        Mtw[i] = f2bf(acc);
    }
}

// ---------------------------------------------------------------------------
// K3 (merged final+pe, MFMA matmul): per 8x8 tile. r10 proven config
// (VGPR 64, LDS 31232, 5 blk/CU). vm0 read f16 at PIXEL-LOCAL ushort
// index P*128+c (see k_fused Phase B comment); xt staging vectorized.
// ---------------------------------------------------------------------------
__global__ __launch_bounds__(256, 4) void k_fp(
    const float* __restrict__ x, const __hip_bfloat16* __restrict__ m2g,
    const float* __restrict__ wsM, const float* __restrict__ bp,
    const float* __restrict__ dw, const float* __restrict__ dwb,
    const float* __restrict__ pw1, const float* __restrict__ pw2,
    float* __restrict__ out)
{
    __shared__ __align__(16) char smem[31232];
    unsigned short* xt  = (unsigned short*)smem;            // PE: 12*12*64 (18432B)
    unsigned short* t1  = (unsigned short*)(smem + 18432);  // PE: 10*10*64 (12800B)
    unsigned short* m2s = (unsigned short*)smem;            // F:  144*64   (18432B)
    unsigned short* vmL = (unsigned short*)(smem + 18432);  // F:  [64][72] (9216B)
    unsigned short* peL = (unsigned short*)smem;            // F late: [64][72], aliases m2s
    const int tid = threadIdx.x, lane = tid & 63, w = tid >> 6;
    const int quad = lane >> 4, col = lane & 15;
    const int bid = blockIdx.x;
    const int b = bid >> 10, tile = bid & 1023;
    const int y0 = (tile >> 5) * 8, x0 = (tile & 31) * 8;
    const int c = lane;

    // ---------------- Phase PE ----------------
    float w1r[9], w2r[9];
#pragma unroll
    for (int k = 0; k < 9; ++k) { w1r[k] = pw1[c*9+k]; w2r[k] = pw2[c*9+k]; }

    for (int i = tid; i < 2304; i += 256) {     // 12*12 pos x 16 c4-groups
        const int pos = i >> 4, c4 = (i & 15) * 4;
        const int yy = pos / 12, xx = pos - yy*12;
        const int gy = y0 + yy - 2, gx = x0 + xx - 2;
        float4 v = {0.f, 0.f, 0.f, 0.f};
        if (gy >= 0 && gy < 256 && gx >= 0 && gx < 256)
            v = *(const float4*)&x[(((size_t)b*256 + gy)*256 + gx)*64 + c4];
        ushort4 us;
        us.x = f2bf(v.x); us.y = f2bf(v.y); us.z = f2bf(v.z); us.w = f2bf(v.w);
        *(ushort4*)&xt[pos*64 + c4] = us;
    }
    __syncthreads();
    for (int i = tid; i < 10*10*64; i += 256) {
        int yy = i / 640, xx = (i % 640) >> 6;
        int gy = y0 + yy - 1, gx = x0 + xx - 1;
        float val = 0.f;
        if (gy >= 0 && gy < 256 && gx >= 0 && gx < 256) {
            float acc = 0.f;
#pragma unroll
            for (int ky = 0; ky < 3; ++ky)
#pragma unroll
                for (int kx = 0; kx < 3; ++kx)
                    acc = fmaf(bf2f(xt[((yy+ky)*12 + xx+kx)*64 + c]),
                               w1r[ky*3+kx], acc);
            val = fast_gelu(acc);
        }
        t1[i] = f2bf(val);
    }
    __syncthreads();

    unsigned peP[4][2];                 // pe bf16-packed: (g, j/2) -> lo=j0 hi=j1
#pragma unroll
    for (int g = 0; g < 4; ++g) {
        const int p0 = w*16 + g*4, py = p0 >> 3, px0 = p0 & 7;
#pragma unroll
        for (int j2 = 0; j2 < 2; ++j2) {
            unsigned pk = 0;
#pragma unroll
            for (int jj = 0; jj < 2; ++jj) {
                const int j = j2*2 + jj;
                float acc = 0.f;
#pragma unroll
                for (int ky = 0; ky < 3; ++ky)
#pragma unroll
                    for (int kx = 0; kx < 3; ++kx)
                        acc = fmaf(bf2f(t1[((py+ky)*10 + px0+j+kx)*64 + c]),
                                   w2r[ky*3+kx], acc);
                pk |= (unsigned)f2bf(acc) << (jj*16);
            }
            peP[g][j2] = pk;
        }
    }
    __syncthreads();                    // PE reads done before LDS realias

    // ---------------- Phase F ----------------
    for (int i2 = tid; i2 < 2304; i2 += 256) {
        const int pos = i2 >> 4, c4 = (i2 & 15) * 4;
        const int yy = pos / 12, xx = pos - yy*12;
        const int gy = y0 + yy - 2, gx = x0 + xx - 2;
        ushort4 us = make_ushort4(0, 0, 0, 0);
        if (gy >= 0 && gy < 256 && gx >= 0 && gx < 256)
            us = *(const ushort4*)&m2g[(((size_t)b*256 + gy)*256 + gx)*64 + c4];
        *(ushort4*)&m2s[pos*64 + c4] = us;
    }
    __syncthreads();

    const float dwbr = dwb[c];
    float dwr[25];
#pragma unroll
    for (int k = 0; k < 25; ++k) dwr[k] = dw[c*25+k];

    const unsigned short* o16 = (const unsigned short*)out;
#pragma unroll
    for (int g = 0; g < 4; ++g) {
        const int p0 = w*16 + g*4;          // 4 consecutive px in one row
        const int py = p0 >> 3, px0 = p0 & 7;
        float acc[4] = {dwbr, dwbr, dwbr, dwbr};
#pragma unroll
        for (int ky = 0; ky < 5; ++ky) {
            const int rbase = ((py+ky)*12 + px0)*64 + c;
#pragma unroll
            for (int kx8 = 0; kx8 < 8; ++kx8) {
                const float tv = bf2f(m2s[rbase + kx8*64]);
#pragma unroll
                for (int j = 0; j < 4; ++j) {
                    const int kk = kx8 - j;
                    if (kk >= 0 && kk < 5)
                        acc[j] = fmaf(tv, dwr[ky*5 + kk], acc[j]);
                }
            }
        }
#pragma unroll
        for (int j = 0; j < 4; ++j) {
            const size_t P = (size_t)b*65536 + (size_t)(y0+py)*256 + (x0+px0+j);
            const float s = fast_sigmoid(acc[j]);
            const float vm0 = __half2float(__ushort_as_half(o16[P*128 + c]));
            vmL[(p0 + j)*72 + c] = f2bf(vm0 * (1.f + s));   // vm bf16
        }
    }
    __syncthreads();                    // all m2s reads + vmL writes complete

    // pe -> LDS (aliases dead m2s) in [px][c] layout for C-layout epilogue
#pragma unroll
    for (int g = 0; g < 4; ++g)
#pragma unroll
        for (int j = 0; j < 4; ++j)
            peL[(w*16 + g*4 + j)*72 + c] =
                (unsigned short)(peP[g][j >> 1] >> ((j & 1)*16));
    __builtin_amdgcn_wave_barrier();
    lds_fence();                        // wave-local peL/vmL visible

    // A-frags: A[m=col(px)][k=quad*8+j+32kh] from vmL
    short8 aV[2];
#pragma unroll
    for (int kh = 0; kh < 2; ++kh)
        aV[kh] = *(const short8*)&vmL[(w*16 + col)*72 + kh*32 + quad*8];
    float bpv[4];
#pragma unroll
    for (int ot = 0; ot < 4; ++ot) bpv[ot] = bp[ot*16 + col];

    const unsigned short* Mtw = (const unsigned short*)wsM + (size_t)b*4096;
#pragma unroll
    for (int ot = 0; ot < 4; ++ot) {
        short8 m0 = *(const short8*)&Mtw[((ot*2+0)*64 + lane)*8];
        short8 m1f = *(const short8*)&Mtw[((ot*2+1)*64 + lane)*8];
        f32x4 a = {0.f, 0.f, 0.f, 0.f};
        a = __builtin_amdgcn_mfma_f32_16x16x32_bf16(aV[0], m0, a, 0,0,0);
        a = __builtin_amdgcn_mfma_f32_16x16x32_bf16(aV[1], m1f, a, 0,0,0);
#pragma unroll
        for (int r = 0; r < 4; ++r) {
            const int pl = w*16 + quad*4 + r;       // C row = px in tile
            const int gy = y0 + (pl >> 3), gx = x0 + (pl & 7);
            out[(((size_t)b*256 + gy)*256 + gx)*64 + ot*16 + col] =
                a[r] + bpv[ot] + bf2f(peL[pl*72 + ot*16 + col]);
        }
    }
}

extern "C" void kernel_launch(void* const* d_in, const int* in_sizes, int n_in,
                              void* d_out, int out_size, void* d_ws, size_t ws_size,
                              hipStream_t stream)
{
    const float* x    = (const float*)d_in[0];
    const float* mask = (const float*)d_in[1];
    const float* Wq   = (const float*)d_in[2];
    const float* Wk   = (const float*)d_in[3];
    const float* Wv   = (const float*)d_in[4];
    const float* resc = (const float*)d_in[5];
    const float* Wp   = (const float*)d_in[6];
    const float* bp   = (const float*)d_in[7];
    const float* mw1  = (const float*)d_in[8];
    const float* mb1  = (const float*)d_in[9];
    const float* mw2  = (const float*)d_in[10];
    const float* mb2  = (const float*)d_in[11];
    const float* mdw  = (const float*)d_in[12];
    const float* mdwb = (const float*)d_in[13];
    const float* pw1  = (const float*)d_in[14];
    const float* pw2  = (const float*)d_in[15];
    float* ws  = (float*)d_ws;
    __hip_bfloat16* m2 = (__hip_bfloat16*)((char*)d_ws + WS_M2_BYTE);
    float* out = (float*)d_out;

    k_fused<<<512,  256, 0, stream>>>(x, mask, Wq, Wk, Wv, mw1, mw2,
                                      mb1, mb2, ws, out, m2);
    k_attn <<<2,    256, 0, stream>>>(resc, Wp, ws);
    k_fp   <<<2048, 256, 0, stream>>>(x, m2, ws + WS_M, bp, mdw, mdwb,
                                      pw1, pw2, out);
}

// Round 15
// 197.046 us; speedup vs baseline: 1.2363x; 1.2363x over previous
//
#include <hip/hip_runtime.h>
#include <hip/hip_bf16.h>
#include <hip/hip_fp16.h>
#include <math.h>

#define BB 2
#define NPIX 131072            // 2*256*256

// ws float header (4-slot accumulators)
#define WS_G    0              // [slot4][B][1024]  (G[c=h*16+d][e])
#define WS_SSQ  8192           // [slot4][2][B][64] (0=q,1=k)
#define WS_M    9216           // 8192 ushort: Mt folded, MFMA-B-frag-swizzled
#define WS_WSWZ_BYTE ((size_t)17408*4)            // 20480 ushort pre-swizzled weights (40 KB)
#define WS_M2_BYTE   (WS_WSWZ_BYTE + 40960)       // m2 bf16: NPIX*64*2 = 16.78 MB

typedef __attribute__((ext_vector_type(8))) short short8;
typedef __attribute__((ext_vector_type(4))) float f32x4;

__device__ __forceinline__ unsigned short f2bf(float f) {
    unsigned u = __float_as_uint(f);
    u += 0x7FFFu + ((u >> 16) & 1u);            // RNE
    return (unsigned short)(u >> 16);
}
__device__ __forceinline__ float bf2f(unsigned short s) {
    return __uint_as_float((unsigned)s << 16);
}
__device__ __forceinline__ void lds_fence() {
    __asm__ __volatile__("s_waitcnt lgkmcnt(0)" ::: "memory");
}
// fast transcendentals (r8: erff/expf -> __expf+v_rcp, confirmed −5us on k_fp)
__device__ __forceinline__ float fast_sigmoid(float a) {
    return __builtin_amdgcn_rcpf(1.f + __expf(-a));
}
__device__ __forceinline__ float fast_gelu(float x) {
    float y = 1.5957691216057308f * fmaf(0.044715f * x, x * x, x);
    return x * fast_sigmoid(y);
}

// ---------------------------------------------------------------------------
// K0: pre-swizzle the 5 weight matrices into MFMA B-frag order, bf16, in ws.
// Also zeroes the G/ssq accumulator header. RESTORED from r12 — r14's
// in-kernel self-swizzle + 256-partial reduction cost ~44us combined.
// ---------------------------------------------------------------------------
__global__ __launch_bounds__(256) void k_prep(const float* __restrict__ Wq,
    const float* __restrict__ Wk, const float* __restrict__ Wv,
    const float* __restrict__ w1, const float* __restrict__ w2,
    unsigned short* __restrict__ wg, float* __restrict__ ws)
{
    const int i = blockIdx.x*256 + threadIdx.x;     // 80 blocks -> 20480
    if (i < 9216) ws[i] = 0.f;                      // zero G + ssq slots
    const int f = i >> 9, l = (i >> 3) & 63, j = i & 7;
    const int matot = f >> 1, kh = f & 1;
    const int mat = matot >> 2, ot = matot & 3;
    const int o = ot*16 + (l & 15);
    const int cc = kh*32 + ((l >> 4) & 3)*8 + j;
    const float* Wsrc[5] = {Wq, Wk, Wv, w1, w2};
    wg[i] = f2bf(Wsrc[mat][o*64 + cc]);
}

// ---------------------------------------------------------------------------
// K1 (MFMA, fused): r12 structure (LDS weights from pre-swizzled wg, 4-slot
// atomic G/ssq — both r14 experiments reverted). ONLY r14 change kept:
// Phase B stores vm0 as f16 PIXEL-LOCAL (ushort idx P*128+c = first half of
// pixel P's own f32 out row; race-free, halves vm0 traffic; r14 refcheck'd).
// LDS = 40(wswz) + 25.5(scr) + 8(ssq) = 73.5 KB -> 2 blocks/CU.
// ---------------------------------------------------------------------------
__global__ __launch_bounds__(256, 2) void k_fused(
    const float* __restrict__ x, const float* __restrict__ mask,
    const unsigned short* __restrict__ wg,
    const float* __restrict__ b1, const float* __restrict__ b2,
    float* __restrict__ ws, float* __restrict__ out,
    __hip_bfloat16* __restrict__ m2out)
{
    __shared__ unsigned short wswz[20480];          // 40 KB
    __shared__ unsigned short scr[4][3264];         // 6.375 KB/wave (25.5 KB)
    __shared__ float s_ssq[4][2][4][64];            // 8 KB [w][mat][ot][lane]
    const int tid = threadIdx.x, lane = tid & 63, w = tid >> 6;
    const int quad = lane >> 4, col = lane & 15;
    const int blk = blockIdx.x, b = blk >> 8, slot = blk & 3;

    for (int i = tid; i < 2560; i += 256)           // 40KB contiguous b128
        ((uint4*)wswz)[i] = ((const uint4*)wg)[i];
    __syncthreads();

    float b1v[4], b2v[4];
#pragma unroll
    for (int ot = 0; ot < 4; ++ot) {
        b1v[ot] = b1[ot*16 + col];
        b2v[ot] = b2[ot*16 + col];
    }

#define WFRAG(matot, kh) (*(const short8*)&wswz[(((matot)*2 + (kh))*64 + lane)*8])

    f32x4 gacc[4];                      // G_h tiles: row d=quad*4+r, col e=lane&15
#pragma unroll
    for (int h = 0; h < 4; ++h) gacc[h] = (f32x4){0.f, 0.f, 0.f, 0.f};
    float ssq[2][4];                    // [mat][ot], channel = ot*16+col
#pragma unroll
    for (int mm = 0; mm < 2; ++mm)
#pragma unroll
        for (int ot = 0; ot < 4; ++ot) ssq[mm][ot] = 0.f;
    const short8 z8 = {0,0,0,0,0,0,0,0};
    unsigned short* S  = scr[w];
    unsigned short* S2 = scr[w] + 2112; // byte 4224, 16B aligned; m1/m2 region

    for (int t = 0; t < 4; ++t) {
        const int pbase = blk*256 + t*64 + w*16;

        // A-frags from global (fp32 -> bf16): A[m=col(px)][k=quad*8+j (+32kh)]
        short8 xA[2], mA[2];
        {
            const float* xs = x    + ((size_t)(pbase + col))*64 + quad*8;
            const float* ms = mask + ((size_t)(pbase + col))*64 + quad*8;
#pragma unroll
            for (int kh = 0; kh < 2; ++kh) {
                float4 a0 = *(const float4*)(xs + kh*32);
                float4 a1 = *(const float4*)(xs + kh*32 + 4);
                float4 b0 = *(const float4*)(ms + kh*32);
                float4 b1f = *(const float4*)(ms + kh*32 + 4);
#pragma unroll
                for (int j = 0; j < 4; ++j) {
                    xA[kh][j]   = (short)f2bf((&a0.x)[j]);
                    xA[kh][4+j] = (short)f2bf((&a1.x)[j]);
                    mA[kh][j]   = (short)f2bf((&b0.x)[j]);
                    mA[kh][4+j] = (short)f2bf((&b1f.x)[j]);
                }
            }
        }

        // Phase A: q,k -> S_t[mat][c][24] bf16 (transposed), ssq in-register
#pragma unroll
        for (int mm = 0; mm < 2; ++mm) {
#pragma unroll
            for (int ot = 0; ot < 4; ++ot) {
                f32x4 a = {0.f, 0.f, 0.f, 0.f};
                a = __builtin_amdgcn_mfma_f32_16x16x32_bf16(xA[0], WFRAG(mm*4+ot,0), a, 0,0,0);
                a = __builtin_amdgcn_mfma_f32_16x16x32_bf16(xA[1], WFRAG(mm*4+ot,1), a, 0,0,0);
#pragma unroll
                for (int r = 0; r < 4; ++r) {
                    S[mm*1536 + (ot*16 + col)*24 + quad*4 + r] = f2bf(a[r]);
                    ssq[mm][ot] = fmaf(a[r], a[r], ssq[mm][ot]);
                }
            }
        }
        __builtin_amdgcn_wave_barrier();

        // Gram via MFMA: G_h[d][e] += sum_p K[p][h16+d]*Q[p][h16+e]
        {
            const int gb = (quad & 1) * 8;
#pragma unroll
            for (int h = 0; h < 4; ++h) {
                short8 aq = *(const short8*)&S[(h*16 + col)*24 + gb];
                short8 ak = *(const short8*)&S[1536 + (h*16 + col)*24 + gb];
                if (quad >= 2) { aq = z8; ak = z8; }
                gacc[h] = __builtin_amdgcn_mfma_f32_16x16x32_bf16(ak, aq, gacc[h], 0,0,0);
            }
        }
        lds_fence();                    // Gram reads done before S_t reused

        // v, m1
        f32x4 vfr[4], m1fr[4];
#pragma unroll
        for (int ot = 0; ot < 4; ++ot) {
            f32x4 a = {0.f, 0.f, 0.f, 0.f};
            a = __builtin_amdgcn_mfma_f32_16x16x32_bf16(xA[0], WFRAG(8+ot,0), a, 0,0,0);
            a = __builtin_amdgcn_mfma_f32_16x16x32_bf16(xA[1], WFRAG(8+ot,1), a, 0,0,0);
            vfr[ot] = a;
        }
#pragma unroll
        for (int ot = 0; ot < 4; ++ot) {
            f32x4 a = {0.f, 0.f, 0.f, 0.f};
            a = __builtin_amdgcn_mfma_f32_16x16x32_bf16(mA[0], WFRAG(12+ot,0), a, 0,0,0);
            a = __builtin_amdgcn_mfma_f32_16x16x32_bf16(mA[1], WFRAG(12+ot,1), a, 0,0,0);
#pragma unroll
            for (int r = 0; r < 4; ++r) a[r] += b1v[ot];
            m1fr[ot] = a;
        }

        // Phase B: vm0 fp32 [16][66] in S, then f16-packed PIXEL-LOCAL stores
        float* vscr = (float*)S;
#pragma unroll
        for (int ot = 0; ot < 4; ++ot)
#pragma unroll
            for (int r = 0; r < 4; ++r)
                vscr[(quad*4+r)*66 + ot*16 + col] = vfr[ot][r] * m1fr[ot][r];
        __builtin_amdgcn_wave_barrier();
        {
            unsigned short* o16 = (unsigned short*)out;
            const int rb = lane >> 5, ci = (lane & 31)*2;
#pragma unroll
            for (int pp = 0; pp < 8; ++pp) {
                const int row = pp*2 + rb;
                float2 v2 = *(const float2*)&vscr[row*66 + ci];
                unsigned pk = (unsigned)__half_as_ushort(__float2half(v2.x))
                            | ((unsigned)__half_as_ushort(__float2half(v2.y)) << 16);
                *(unsigned*)&o16[((size_t)(pbase + row))*128 + ci] = pk;
            }
        }
        // no fence: Phase C writes S2 (disjoint from vscr)

        // Phase C: m1 bf16 [16][72] in S2 -> A-frags for m2
#pragma unroll
        for (int ot = 0; ot < 4; ++ot)
#pragma unroll
            for (int r = 0; r < 4; ++r)
                S2[(quad*4+r)*72 + ot*16 + col] = f2bf(m1fr[ot][r]);
        __builtin_amdgcn_wave_barrier();
        short8 a2[2];
#pragma unroll
        for (int kh = 0; kh < 2; ++kh)
            a2[kh] = *(const short8*)&S2[col*72 + kh*32 + quad*8];
        lds_fence();                    // a2 reads done before S2 overwritten

        // Phase D: m2 mfma, bf16 [16][72] in S2, coalesced packed-uint stores
#pragma unroll
        for (int ot = 0; ot < 4; ++ot) {
            f32x4 a = {0.f, 0.f, 0.f, 0.f};
            a = __builtin_amdgcn_mfma_f32_16x16x32_bf16(a2[0], WFRAG(16+ot,0), a, 0,0,0);
            a = __builtin_amdgcn_mfma_f32_16x16x32_bf16(a2[1], WFRAG(16+ot,1), a, 0,0,0);
#pragma unroll
            for (int r = 0; r < 4; ++r)
                S2[(quad*4+r)*72 + ot*16 + col] = f2bf(a[r] + b2v[ot]);
        }
        __builtin_amdgcn_wave_barrier();
        {
            unsigned short* m2u = (unsigned short*)m2out;
            const int rb = lane >> 5, ci = (lane & 31)*2;
#pragma unroll
            for (int pp = 0; pp < 8; ++pp) {
                const int row = pp*2 + rb;
                unsigned vv = *(const unsigned*)&S2[row*72 + ci];
                *(unsigned*)&m2u[((size_t)(pbase + row))*64 + ci] = vv;
            }
        }
        lds_fence();                    // all reads done before next-iter A
    }

    __syncthreads();                    // all waves done with scr

    // two-phase block reduction of G; gr indexed by idx = c*16+e directly
    float* gr = (float*)&scr[0][0];     // 2048 floats (8KB) in 25.5KB scr
    if (w < 2) {
#pragma unroll
        for (int h = 0; h < 4; ++h)
#pragma unroll
            for (int r = 0; r < 4; ++r)
                gr[w*1024 + (h*16 + quad*4 + r)*16 + col] = gacc[h][r];
    }
#pragma unroll
    for (int mm = 0; mm < 2; ++mm)
#pragma unroll
        for (int ot = 0; ot < 4; ++ot)
            s_ssq[w][mm][ot][lane] = ssq[mm][ot];
    __syncthreads();
    if (w >= 2) {
#pragma unroll
        for (int h = 0; h < 4; ++h)
#pragma unroll
            for (int r = 0; r < 4; ++r)
                gr[(w-2)*1024 + (h*16 + quad*4 + r)*16 + col] += gacc[h][r];
    }
    __syncthreads();
    float* Gg = ws + WS_G + (size_t)slot*2048 + (size_t)b*1024;
    for (int idx = tid; idx < 1024; idx += 256)
        atomicAdd(&Gg[idx], gr[idx] + gr[1024 + idx]);
    if (tid < 128) {
        const int which = tid >> 6, cidx = tid & 63;
        const int ot = cidx >> 4, cl = cidx & 15;
        float s = 0.f;
#pragma unroll
        for (int wv = 0; wv < 4; ++wv)
#pragma unroll
            for (int q = 0; q < 4; ++q)
                s += s_ssq[wv][which][ot][q*16 + cl];
        atomicAdd(ws + WS_SSQ + (size_t)slot*256 + which*128 + b*64 + cidx, s);
    }
#undef WFRAG
}

// ---------------------------------------------------------------------------
// K2: softmax over normalized Gram (sum 4 slots), folded with Wp.
// Output written as bf16 MFMA-B-frags so k_fp reads frags from global.
// ---------------------------------------------------------------------------
__global__ __launch_bounds__(256) void k_attn(const float* __restrict__ rescale,
    const float* __restrict__ Wp, float* __restrict__ ws)
{
    __shared__ float sAtt[1024];        // [h][d][e]
    const int b = blockIdx.x, t = threadIdx.x;
    const int d = t >> 4, e = t & 15;
#pragma unroll
    for (int h = 0; h < 4; ++h) {
        float g = 0.f, nk2 = 0.f, nq2 = 0.f;
#pragma unroll
        for (int s = 0; s < 4; ++s) {
            g   += ws[WS_G + s*2048 + b*1024 + (h*16+d)*16 + e];
            nk2 += ws[WS_SSQ + s*256 + 128 + b*64 + h*16 + d];
            nq2 += ws[WS_SSQ + s*256 +   0 + b*64 + h*16 + e];
        }
        float nk = fmaxf(sqrtf(nk2), 1e-12f);
        float nq = fmaxf(sqrtf(nq2), 1e-12f);
        float val = g / (nk*nq) * rescale[h];
        float m = val;
        for (int off = 1; off < 16; off <<= 1) m = fmaxf(m, __shfl_xor(m, off, 16));
        float ev = expf(val - m);
        float s2 = ev;
        for (int off = 1; off < 16; off <<= 1) s2 += __shfl_xor(s2, off, 16);
        sAtt[h*256 + d*16 + e] = ev / s2;
    }
    __syncthreads();
    // Mt[c][o] = sum_d Wp[o][h*16+d]*att[h][d][e(c)], written B-frag-swizzled
    unsigned short* Mtw = (unsigned short*)(ws + WS_M) + (size_t)b*4096;
    for (int i = t; i < 4096; i += 256) {
        const int f = i >> 9, l = (i >> 3) & 63, j = i & 7;
        const int ot = f >> 1, kh = f & 1;
        const int o = ot*16 + (l & 15);
        const int cc = kh*32 + ((l >> 4) & 3)*8 + j;
        const int h = cc >> 4, ee = cc & 15;
        float acc = 0.f;
#pragma unroll
        for (int d2 = 0; d2 < 16; ++d2)
            acc = fmaf(Wp[o*64 + h*16 + d2], sAtt[h*256 + d2*16 + ee], acc);
        Mtw[i] = f2bf(acc);
    }
}

// ---------------------------------------------------------------------------
// K3 (merged final+pe, MFMA matmul): r14 form VERBATIM (57.0us measured:
// VGPR 64, LDS 31232, FETCH 44.9MB). vm0 read f16 at pixel-local P*128+c;
// xt staging vectorized.
// ---------------------------------------------------------------------------
__global__ __launch_bounds__(256, 4) void k_fp(
    const float* __restrict__ x, const __hip_bfloat16* __restrict__ m2g,
    const float* __restrict__ wsM, const float* __restrict__ bp,
    const float* __restrict__ dw, const float* __restrict__ dwb,
    const float* __restrict__ pw1, const float* __restrict__ pw2,
    float* __restrict__ out)
{
    __shared__ __align__(16) char smem[31232];
    unsigned short* xt  = (unsigned short*)smem;            // PE: 12*12*64 (18432B)
    unsigned short* t1  = (unsigned short*)(smem + 18432);  // PE: 10*10*64 (12800B)
    unsigned short* m2s = (unsigned short*)smem;            // F:  144*64   (18432B)
    unsigned short* vmL = (unsigned short*)(smem + 18432);  // F:  [64][72] (9216B)
    unsigned short* peL = (unsigned short*)smem;            // F late: [64][72], aliases m2s
    const int tid = threadIdx.x, lane = tid & 63, w = tid >> 6;
    const int quad = lane >> 4, col = lane & 15;
    const int bid = blockIdx.x;
    const int b = bid >> 10, tile = bid & 1023;
    const int y0 = (tile >> 5) * 8, x0 = (tile & 31) * 8;
    const int c = lane;

    // ---------------- Phase PE ----------------
    float w1r[9], w2r[9];
#pragma unroll
    for (int k = 0; k < 9; ++k) { w1r[k] = pw1[c*9+k]; w2r[k] = pw2[c*9+k]; }

    for (int i = tid; i < 2304; i += 256) {     // 12*12 pos x 16 c4-groups
        const int pos = i >> 4, c4 = (i & 15) * 4;
        const int yy = pos / 12, xx = pos - yy*12;
        const int gy = y0 + yy - 2, gx = x0 + xx - 2;
        float4 v = {0.f, 0.f, 0.f, 0.f};
        if (gy >= 0 && gy < 256 && gx >= 0 && gx < 256)
            v = *(const float4*)&x[(((size_t)b*256 + gy)*256 + gx)*64 + c4];
        ushort4 us;
        us.x = f2bf(v.x); us.y = f2bf(v.y); us.z = f2bf(v.z); us.w = f2bf(v.w);
        *(ushort4*)&xt[pos*64 + c4] = us;
    }
    __syncthreads();
    for (int i = tid; i < 10*10*64; i += 256) {
        int yy = i / 640, xx = (i % 640) >> 6;
        int gy = y0 + yy - 1, gx = x0 + xx - 1;
        float val = 0.f;
        if (gy >= 0 && gy < 256 && gx >= 0 && gx < 256) {
            float acc = 0.f;
#pragma unroll
            for (int ky = 0; ky < 3; ++ky)
#pragma unroll
                for (int kx = 0; kx < 3; ++kx)
                    acc = fmaf(bf2f(xt[((yy+ky)*12 + xx+kx)*64 + c]),
                               w1r[ky*3+kx], acc);
            val = fast_gelu(acc);
        }
        t1[i] = f2bf(val);
    }
    __syncthreads();

    unsigned peP[4][2];                 // pe bf16-packed: (g, j/2) -> lo=j0 hi=j1
#pragma unroll
    for (int g = 0; g < 4; ++g) {
        const int p0 = w*16 + g*4, py = p0 >> 3, px0 = p0 & 7;
#pragma unroll
        for (int j2 = 0; j2 < 2; ++j2) {
            unsigned pk = 0;
#pragma unroll
            for (int jj = 0; jj < 2; ++jj) {
                const int j = j2*2 + jj;
                float acc = 0.f;
#pragma unroll
                for (int ky = 0; ky < 3; ++ky)
#pragma unroll
                    for (int kx = 0; kx < 3; ++kx)
                        acc = fmaf(bf2f(t1[((py+ky)*10 + px0+j+kx)*64 + c]),
                                   w2r[ky*3+kx], acc);
                pk |= (unsigned)f2bf(acc) << (jj*16);
            }
            peP[g][j2] = pk;
        }
    }
    __syncthreads();                    // PE reads done before LDS realias

    // ---------------- Phase F ----------------
    for (int i2 = tid; i2 < 2304; i2 += 256) {
        const int pos = i2 >> 4, c4 = (i2 & 15) * 4;
        const int yy = pos / 12, xx = pos - yy*12;
        const int gy = y0 + yy - 2, gx = x0 + xx - 2;
        ushort4 us = make_ushort4(0, 0, 0, 0);
        if (gy >= 0 && gy < 256 && gx >= 0 && gx < 256)
            us = *(const ushort4*)&m2g[(((size_t)b*256 + gy)*256 + gx)*64 + c4];
        *(ushort4*)&m2s[pos*64 + c4] = us;
    }
    __syncthreads();

    const float dwbr = dwb[c];
    float dwr[25];
#pragma unroll
    for (int k = 0; k < 25; ++k) dwr[k] = dw[c*25+k];

    const unsigned short* o16 = (const unsigned short*)out;
#pragma unroll
    for (int g = 0; g < 4; ++g) {
        const int p0 = w*16 + g*4;          // 4 consecutive px in one row
        const int py = p0 >> 3, px0 = p0 & 7;
        float acc[4] = {dwbr, dwbr, dwbr, dwbr};
#pragma unroll
        for (int ky = 0; ky < 5; ++ky) {
            const int rbase = ((py+ky)*12 + px0)*64 + c;
#pragma unroll
            for (int kx8 = 0; kx8 < 8; ++kx8) {
                const float tv = bf2f(m2s[rbase + kx8*64]);
#pragma unroll
                for (int j = 0; j < 4; ++j) {
                    const int kk = kx8 - j;
                    if (kk >= 0 && kk < 5)
                        acc[j] = fmaf(tv, dwr[ky*5 + kk], acc[j]);
                }
            }
        }
#pragma unroll
        for (int j = 0; j < 4; ++j) {
            const size_t P = (size_t)b*65536 + (size_t)(y0+py)*256 + (x0+px0+j);
            const float s = fast_sigmoid(acc[j]);
            const float vm0 = __half2float(__ushort_as_half(o16[P*128 + c]));
            vmL[(p0 + j)*72 + c] = f2bf(vm0 * (1.f + s));   // vm bf16
        }
    }
    __syncthreads();                    // all m2s reads + vmL writes complete

    // pe -> LDS (aliases dead m2s) in [px][c] layout for C-layout epilogue
#pragma unroll
    for (int g = 0; g < 4; ++g)
#pragma unroll
        for (int j = 0; j < 4; ++j)
            peL[(w*16 + g*4 + j)*72 + c] =
                (unsigned short)(peP[g][j >> 1] >> ((j & 1)*16));
    __builtin_amdgcn_wave_barrier();
    lds_fence();                        // wave-local peL/vmL visible

    // A-frags: A[m=col(px)][k=quad*8+j+32kh] from vmL
    short8 aV[2];
#pragma unroll
    for (int kh = 0; kh < 2; ++kh)
        aV[kh] = *(const short8*)&vmL[(w*16 + col)*72 + kh*32 + quad*8];
    float bpv[4];
#pragma unroll
    for (int ot = 0; ot < 4; ++ot) bpv[ot] = bp[ot*16 + col];

    const unsigned short* Mtw = (const unsigned short*)wsM + (size_t)b*4096;
#pragma unroll
    for (int ot = 0; ot < 4; ++ot) {
        short8 m0 = *(const short8*)&Mtw[((ot*2+0)*64 + lane)*8];
        short8 m1f = *(const short8*)&Mtw[((ot*2+1)*64 + lane)*8];
        f32x4 a = {0.f, 0.f, 0.f, 0.f};
        a = __builtin_amdgcn_mfma_f32_16x16x32_bf16(aV[0], m0, a, 0,0,0);
        a = __builtin_amdgcn_mfma_f32_16x16x32_bf16(aV[1], m1f, a, 0,0,0);
#pragma unroll
        for (int r = 0; r < 4; ++r) {
            const int pl = w*16 + quad*4 + r;       // C row = px in tile
            const int gy = y0 + (pl >> 3), gx = x0 + (pl & 7);
            out[(((size_t)b*256 + gy)*256 + gx)*64 + ot*16 + col] =
                a[r] + bpv[ot] + bf2f(peL[pl*72 + ot*16 + col]);
        }
    }
}

extern "C" void kernel_launch(void* const* d_in, const int* in_sizes, int n_in,
                              void* d_out, int out_size, void* d_ws, size_t ws_size,
                              hipStream_t stream)
{
    const float* x    = (const float*)d_in[0];
    const float* mask = (const float*)d_in[1];
    const float* Wq   = (const float*)d_in[2];
    const float* Wk   = (const float*)d_in[3];
    const float* Wv   = (const float*)d_in[4];
    const float* resc = (const float*)d_in[5];
    const float* Wp   = (const float*)d_in[6];
    const float* bp   = (const float*)d_in[7];
    const float* mw1  = (const float*)d_in[8];
    const float* mb1  = (const float*)d_in[9];
    const float* mw2  = (const float*)d_in[10];
    const float* mb2  = (const float*)d_in[11];
    const float* mdw  = (const float*)d_in[12];
    const float* mdwb = (const float*)d_in[13];
    const float* pw1  = (const float*)d_in[14];
    const float* pw2  = (const float*)d_in[15];
    float* ws  = (float*)d_ws;
    unsigned short* wg = (unsigned short*)((char*)d_ws + WS_WSWZ_BYTE);
    __hip_bfloat16* m2 = (__hip_bfloat16*)((char*)d_ws + WS_M2_BYTE);
    float* out = (float*)d_out;

    k_prep <<<80,   256, 0, stream>>>(Wq, Wk, Wv, mw1, mw2, wg, ws);
    k_fused<<<512,  256, 0, stream>>>(x, mask, wg, mb1, mb2, ws, out, m2);
    k_attn <<<2,    256, 0, stream>>>(resc, Wp, ws);
    k_fp   <<<2048, 256, 0, stream>>>(x, m2, ws + WS_M, bp, mdw, mdwb,
                                      pw1, pw2, out);
}